// Round 1
// baseline (777.688 us; speedup 1.0000x reference)
//
#include <hip/hip_runtime.h>
#include <hip/hip_bf16.h>

#define NN 32768
#define NE 524288
#define FF 128
#define NRBF 32
#define NFEAT 36
#define NBATCH 16

// ---------------------------------------------------------------------------
// Kernel 1: per-node transforms.
// q_inv = silu(x @ Wq), k_inv = silu(x @ Wk), v_inv = x @ Wv,
// q_ev = silu(x @ Wqe), k_ev = silu(x @ Wke)   -- all per-head 32x32.
// One block per node, 128 threads: thread t -> (head h = t/32, col e = t%32).
// ---------------------------------------------------------------------------
__global__ __launch_bounds__(128) void node_kernel(
    const float* __restrict__ x,
    const float* __restrict__ Wq, const float* __restrict__ Wk,
    const float* __restrict__ Wv, const float* __restrict__ Wqe,
    const float* __restrict__ Wke,
    float* __restrict__ QI, float* __restrict__ KI, float* __restrict__ VI,
    float* __restrict__ QE, float* __restrict__ KE)
{
    __shared__ float xs[128];
    const int n = blockIdx.x;
    const int t = threadIdx.x;
    xs[t] = x[n * FF + t];
    __syncthreads();
    const int h = t >> 5;
    const int e = t & 31;
    const float* xh = &xs[h * 32];
    const int wb = h * 1024 + e;       // W[h, d, e] = W[h*1024 + d*32 + e]
    float aq = 0.f, ak = 0.f, av = 0.f, aqe = 0.f, ake = 0.f;
#pragma unroll
    for (int d = 0; d < 32; ++d) {
        const float xv = xh[d];
        aq  += xv * Wq [wb + d * 32];
        ak  += xv * Wk [wb + d * 32];
        av  += xv * Wv [wb + d * 32];
        aqe += xv * Wqe[wb + d * 32];
        ake += xv * Wke[wb + d * 32];
    }
    const int o = n * FF + t;
    QI[o] = aq  / (1.f + __expf(-aq));
    KI[o] = ak  / (1.f + __expf(-ak));
    VI[o] = av;
    QE[o] = aqe / (1.f + __expf(-aqe));
    KE[o] = ake / (1.f + __expf(-ake));
}

// ---------------------------------------------------------------------------
// Kernel 2: per-edge attention + scatter.
// One wave processes NBATCH=16 edges at a time:
//   A) stage rbf rows into per-wave LDS feat buffer (coalesced float4)
//   B) lanes 0..15: compute per-degree invariants from ev_features diffs
//   C) register-blocked GEMM feat[16,36] @ Wf[36,256] (Wf in LDS, float2/lane)
//   D) per edge: gather q/k/v (coalesced float2), head/degree dot via
//      16-lane shfl_xor reduce, atomicAdd into d_inv / d_ev.
// ---------------------------------------------------------------------------
__global__ __launch_bounds__(256) void edge_kernel(
    const float* __restrict__ ev_feat,   // [N,16]
    const float* __restrict__ rbf,       // [E,32]
    const float* __restrict__ sh,        // [E,16]
    const float* __restrict__ cutoffs,   // [E]
    const float* __restrict__ WfInv,     // [36,128]
    const float* __restrict__ bfInv,     // [128]
    const float* __restrict__ WfEv,      // [36,128]
    const float* __restrict__ bfEv,      // [128]
    const int* __restrict__ senders,
    const int* __restrict__ receivers,
    const float* __restrict__ QI, const float* __restrict__ KI,
    const float* __restrict__ VI, const float* __restrict__ QE,
    const float* __restrict__ KE,
    float* __restrict__ dinv,            // [N,128]  (d_out)
    float* __restrict__ devout)          // [N,16]   (d_out + N*128)
{
    __shared__ float wfi[NFEAT * 128];
    __shared__ float wfe[NFEAT * 128];
    __shared__ float feat_s[4][NBATCH][NFEAT];
    __shared__ float cut_s[4][NBATCH];
    __shared__ int   sid_s[4][NBATCH];
    __shared__ int   rid_s[4][NBATCH];

    for (int i = threadIdx.x; i < NFEAT * 128; i += 256) {
        wfi[i] = WfInv[i];
        wfe[i] = WfEv[i];
    }
    __syncthreads();

    const int wave = threadIdx.x >> 6;
    const int lane = threadIdx.x & 63;
    const int c0 = lane * 2;
    const float bi0 = bfInv[c0], bi1 = bfInv[c0 + 1];
    const float be0 = bfEv[c0], be1 = bfEv[c0 + 1];
    const float rs32 = 0.17677669529663687f;   // 1/sqrt(32)

    const int nbatches = NE / NBATCH;          // 32768
    const int gw = blockIdx.x * 4 + wave;
    const int nw = gridDim.x * 4;

    for (int bi = gw; bi < nbatches; bi += nw) {
        const int ebase = bi * NBATCH;

        // ---- phase A: rbf -> feat_s (4 lanes per edge, 32B each) ----
        {
            const int b = lane >> 2;      // edge in batch
            const int chunk = lane & 3;   // 8-float chunk
            const float4* src =
                (const float4*)&rbf[(ebase + b) * NRBF + chunk * 8];
            const float4 v0 = src[0], v1 = src[1];
            float* dst = &feat_s[wave][b][chunk * 8];
            dst[0] = v0.x; dst[1] = v0.y; dst[2] = v0.z; dst[3] = v0.w;
            dst[4] = v1.x; dst[5] = v1.y; dst[6] = v1.z; dst[7] = v1.w;
        }
        // ---- phase B: invariants + per-edge scalars (lanes 0..15) ----
        if (lane < NBATCH) {
            const int e = ebase + lane;
            const int s = senders[e];
            const int r = receivers[e];
            sid_s[wave][lane] = s;
            rid_s[wave][lane] = r;
            cut_s[wave][lane] = cutoffs[e];
            const float* es = &ev_feat[s * 16];
            const float* er = &ev_feat[r * 16];
            float d0 = es[0] - er[0];
            float i0 = d0 * d0;
            float i1 = 0.f, i2 = 0.f, i3 = 0.f;
#pragma unroll
            for (int k = 1; k < 4; ++k) { float d = es[k] - er[k]; i1 += d * d; }
#pragma unroll
            for (int k = 4; k < 9; ++k) { float d = es[k] - er[k]; i2 += d * d; }
#pragma unroll
            for (int k = 9; k < 16; ++k) { float d = es[k] - er[k]; i3 += d * d; }
            feat_s[wave][lane][32] = i0;
            feat_s[wave][lane][33] = i1;
            feat_s[wave][lane][34] = i2;
            feat_s[wave][lane][35] = i3;
        }
        // intra-wave LDS producer->consumer fence (no cross-wave sharing)
        asm volatile("s_waitcnt lgkmcnt(0)" ::: "memory");
        __builtin_amdgcn_sched_barrier(0);

        // ---- phase C: feat @ Wf for 16 edges, cols (c0, c0+1) per lane ----
        float fwi0[NBATCH], fwi1[NBATCH], fwe0[NBATCH], fwe1[NBATCH];
#pragma unroll
        for (int b = 0; b < NBATCH; ++b) {
            fwi0[b] = bi0; fwi1[b] = bi1; fwe0[b] = be0; fwe1[b] = be1;
        }
#pragma unroll 4
        for (int j = 0; j < NFEAT; ++j) {
            const float2 wi = *(const float2*)&wfi[j * 128 + c0];
            const float2 we = *(const float2*)&wfe[j * 128 + c0];
#pragma unroll
            for (int b = 0; b < NBATCH; ++b) {
                const float fj = feat_s[wave][b][j];
                fwi0[b] += fj * wi.x; fwi1[b] += fj * wi.y;
                fwe0[b] += fj * we.x; fwe1[b] += fj * we.y;
            }
        }

        // ---- phase D: attention dots + scatter ----
#pragma unroll
        for (int b = 0; b < NBATCH; ++b) {
            const int s = sid_s[wave][b];
            const int r = rid_s[wave][b];
            const float cut = cut_s[wave][b];
            const float2 qi = *(const float2*)&QI[r * FF + c0];
            const float2 ki = *(const float2*)&KI[s * FF + c0];
            const float2 vi = *(const float2*)&VI[s * FF + c0];
            const float2 qe = *(const float2*)&QE[r * FF + c0];
            const float2 ke = *(const float2*)&KE[s * FF + c0];
            float pi = qi.x * ki.x * fwi0[b] + qi.y * ki.y * fwi1[b];
            float pe = qe.x * ke.x * fwe0[b] + qe.y * ke.y * fwe1[b];
#pragma unroll
            for (int off = 1; off < 16; off <<= 1) {
                pi += __shfl_xor(pi, off, 64);
                pe += __shfl_xor(pe, off, 64);
            }
            // pi = per-head (head = lane/16) raw attention sum; same for pe.
            const float coef = cut * pi * rs32;
            atomicAdd(&dinv[r * FF + c0],     coef * vi.x);
            atomicAdd(&dinv[r * FF + c0 + 1], coef * vi.y);
            // ev path: lane k<16 needs a_ev[deg(k)], value lives in lane 16*deg
            const int dsel = (lane >= 9) ? 48 : (lane >= 4) ? 32
                           : (lane >= 1) ? 16 : 0;
            const float aev = __shfl(pe, dsel, 64) * rs32;
            if (lane < 16) {
                const float m = cut * aev * sh[(ebase + b) * 16 + lane];
                atomicAdd(&devout[r * 16 + lane], m);
            }
        }
    }
}

// ---------------------------------------------------------------------------
extern "C" void kernel_launch(void* const* d_in, const int* in_sizes, int n_in,
                              void* d_out, int out_size, void* d_ws,
                              size_t ws_size, hipStream_t stream) {
    const float* inv_features = (const float*)d_in[0];
    const float* ev_features  = (const float*)d_in[1];
    const float* rbf          = (const float*)d_in[2];
    const float* sh_vectors   = (const float*)d_in[3];
    const float* cutoffs      = (const float*)d_in[4];
    const float* W_q_inv      = (const float*)d_in[5];
    const float* W_k_inv      = (const float*)d_in[6];
    const float* W_v_inv      = (const float*)d_in[7];
    const float* W_q_ev       = (const float*)d_in[8];
    const float* W_k_ev       = (const float*)d_in[9];
    const float* Wf_inv       = (const float*)d_in[10];
    // const float* bf_inv    = (const float*)d_in[11];
    const float* Wf_ev        = (const float*)d_in[12];
    // const float* bf_ev     = (const float*)d_in[13];
    const int*   senders      = (const int*)d_in[14];
    const int*   receivers    = (const int*)d_in[15];
    const float* bf_inv       = (const float*)d_in[11];
    const float* bf_ev        = (const float*)d_in[13];

    float* QI = (float*)d_ws;
    float* KI = QI + (size_t)NN * FF;
    float* VI = KI + (size_t)NN * FF;
    float* QE = VI + (size_t)NN * FF;
    float* KE = QE + (size_t)NN * FF;

    float* dinv   = (float*)d_out;               // [N,128]
    float* devout = dinv + (size_t)NN * FF;      // [N,16]

    // outputs are accumulated via atomics -> must start from zero
    hipMemsetAsync(d_out, 0, (size_t)out_size * sizeof(float), stream);

    node_kernel<<<NN, 128, 0, stream>>>(inv_features, W_q_inv, W_k_inv,
                                        W_v_inv, W_q_ev, W_k_ev,
                                        QI, KI, VI, QE, KE);

    edge_kernel<<<4096, 256, 0, stream>>>(ev_features, rbf, sh_vectors,
                                          cutoffs, Wf_inv, bf_inv, Wf_ev,
                                          bf_ev, senders, receivers,
                                          QI, KI, VI, QE, KE, dinv, devout);
}